// Round 18
// baseline (237.648 us; speedup 1.0000x reference)
//
#include <hip/hip_runtime.h>
#include <hip/hip_bf16.h>
#include <math.h>

// y[n,o] = min_i (x[n,i] + w[o,i]) + bias[o]
// x: (32768,128) f32, w: (128,128) f32, bias: (128,) f32, out: (32768,128) f32
//
// Anti-convoy build of the f16 LDS structure (R10 family):
//  1. Explicit 2-deep REGISTER pipeline (named A/B sets): ds_reads for kc+1
//     issue before compute of kc -> counted lgkmcnt, latency hidden per-wave.
//  2. Per-wave ROTATED kc order (min is order-independent): waves start at
//     different kc -> LDS pipe demand de-phased, no burst convoy.
// Geometry: BM=64 x BN=128 (x staged/fetched ONCE), 256 thr, 4x8 tile ->
// 12 ds_read_b128 per 256 pk-VALU per kc; grid 512 = 2 blocks/CU.

typedef __fp16 h2 __attribute__((ext_vector_type(2)));
typedef __fp16 h4 __attribute__((ext_vector_type(4)));
typedef __fp16 h8 __attribute__((ext_vector_type(8)));

constexpr int K     = 128;
constexpr int BM    = 64;
constexpr int LDRH2 = 68;        // row stride in h2 units (272 B, 16B-aligned)

__global__ __launch_bounds__(256, 2)
void minplus_kernel(const float* __restrict__ x,
                    const float* __restrict__ w,
                    const float* __restrict__ bias,
                    float* __restrict__ out)
{
    __shared__ h2 lds[(BM + 128) * LDRH2];   // 52,224 B
    h2* xs = lds;
    h2* ws = lds + BM * LDRH2;

    const int tid = threadIdx.x;
    const float* xsrc = x + (size_t)blockIdx.x * BM * K;

    // ---- stage x (64x128) and w (128x128), f32 -> f16, coalesced ----
    #pragma unroll
    for (int p = 0; p < 8; ++p) {
        int c   = p * 256 + tid;             // 0..2047
        int row = c >> 5;                    // 0..63
        int q   = c & 31;
        float4 v = *(const float4*)(xsrc + row * K + q * 4);
        h2 a = __builtin_amdgcn_cvt_pkrtz(v.x, v.y);
        h2 b = __builtin_amdgcn_cvt_pkrtz(v.z, v.w);
        *(h4*)(xs + row * LDRH2 + q * 2) = __builtin_shufflevector(a, b, 0, 1, 2, 3);
    }
    #pragma unroll
    for (int p = 0; p < 16; ++p) {
        int c   = p * 256 + tid;             // 0..4095
        int row = c >> 5;                    // 0..127
        int q   = c & 31;
        float4 v = *(const float4*)(w + row * K + q * 4);
        h2 a = __builtin_amdgcn_cvt_pkrtz(v.x, v.y);
        h2 b = __builtin_amdgcn_cvt_pkrtz(v.z, v.w);
        *(h4*)(ws + row * LDRH2 + q * 2) = __builtin_shufflevector(a, b, 0, 1, 2, 3);
    }
    __syncthreads();                         // the ONLY barrier

    const int ty = tid >> 4;                 // 0..15 : rows ty + 16m, m=0..3
    const int tx = tid & 15;                 // 0..15 : cols tx + 16n, n=0..7
    const h2* xbp = xs + ty * LDRH2;
    const h2* wbp = ws + tx * LDRH2;

    // de-phase: wave w of block b starts at kc = 2*w + 8*(b&1)
    const int roff = (((tid >> 6) << 1) + ((blockIdx.x & 1) << 3)) & 15;

    h2 hbig;
    hbig.x = (__fp16)65504.0f;
    hbig.y = (__fp16)65504.0f;
    h2 acc[4][8];
    #pragma unroll
    for (int m = 0; m < 4; ++m)
        #pragma unroll
        for (int n = 0; n < 8; ++n)
            acc[m][n] = hbig;

    h8 xA0, xA1, xA2, xA3, wA0, wA1, wA2, wA3, wA4, wA5, wA6, wA7;
    h8 xB0, xB1, xB2, xB3, wB0, wB1, wB2, wB3, wB4, wB5, wB6, wB7;

#define LOADSET(X0, X1, X2, X3, W0, W1, W2, W3, W4, W5, W6, W7, KC)           \
    {                                                                         \
        const h2* _xp = xbp + (KC) * 4;                                       \
        const h2* _wp = wbp + (KC) * 4;                                       \
        X0 = *(const h8*)(_xp + 0 * 16 * LDRH2);                              \
        X1 = *(const h8*)(_xp + 1 * 16 * LDRH2);                              \
        X2 = *(const h8*)(_xp + 2 * 16 * LDRH2);                              \
        X3 = *(const h8*)(_xp + 3 * 16 * LDRH2);                              \
        W0 = *(const h8*)(_wp + 0 * 16 * LDRH2);                              \
        W1 = *(const h8*)(_wp + 1 * 16 * LDRH2);                              \
        W2 = *(const h8*)(_wp + 2 * 16 * LDRH2);                              \
        W3 = *(const h8*)(_wp + 3 * 16 * LDRH2);                              \
        W4 = *(const h8*)(_wp + 4 * 16 * LDRH2);                              \
        W5 = *(const h8*)(_wp + 5 * 16 * LDRH2);                              \
        W6 = *(const h8*)(_wp + 6 * 16 * LDRH2);                              \
        W7 = *(const h8*)(_wp + 7 * 16 * LDRH2);                              \
    }

#define UPD(m, n, XV, WV)                                                     \
    {                                                                         \
        h8 t  = XV + WV;                     /* 4x v_pk_add_f16 */            \
        h2 t0 = __builtin_shufflevector(t, t, 0, 1);                          \
        h2 t1 = __builtin_shufflevector(t, t, 2, 3);                          \
        h2 t2 = __builtin_shufflevector(t, t, 4, 5);                          \
        h2 t3 = __builtin_shufflevector(t, t, 6, 7);                          \
        h2 u  = __builtin_elementwise_min(t0, t1);                            \
        h2 v  = __builtin_elementwise_min(t2, t3);                            \
        h2 uv = __builtin_elementwise_min(u, v);                              \
        acc[m][n] = __builtin_elementwise_min(acc[m][n], uv);                 \
    }
#define ROW8(m, XV, W0, W1, W2, W3, W4, W5, W6, W7)                           \
    UPD(m, 0, XV, W0) UPD(m, 1, XV, W1) UPD(m, 2, XV, W2) UPD(m, 3, XV, W3)   \
    UPD(m, 4, XV, W4) UPD(m, 5, XV, W5) UPD(m, 6, XV, W6) UPD(m, 7, XV, W7)
#define COMPSET(X0, X1, X2, X3, W0, W1, W2, W3, W4, W5, W6, W7)               \
    ROW8(0, X0, W0, W1, W2, W3, W4, W5, W6, W7)                               \
    ROW8(1, X1, W0, W1, W2, W3, W4, W5, W6, W7)                               \
    ROW8(2, X2, W0, W1, W2, W3, W4, W5, W6, W7)                               \
    ROW8(3, X3, W0, W1, W2, W3, W4, W5, W6, W7)

    // ---- software-pipelined k-loop: load(kc+1) issued before compute(kc) ----
    LOADSET(xA0, xA1, xA2, xA3, wA0, wA1, wA2, wA3, wA4, wA5, wA6, wA7, roff)
    #pragma unroll
    for (int i = 0; i < 16; i += 2) {
        const int k1 = (i + 1 + roff) & 15;
        LOADSET(xB0, xB1, xB2, xB3, wB0, wB1, wB2, wB3, wB4, wB5, wB6, wB7, k1)
        COMPSET(xA0, xA1, xA2, xA3, wA0, wA1, wA2, wA3, wA4, wA5, wA6, wA7)
        if (i + 2 < 16) {
            const int k2 = (i + 2 + roff) & 15;
            LOADSET(xA0, xA1, xA2, xA3, wA0, wA1, wA2, wA3, wA4, wA5, wA6, wA7, k2)
        }
        COMPSET(xB0, xB1, xB2, xB3, wB0, wB1, wB2, wB3, wB4, wB5, wB6, wB7)
    }
#undef COMPSET
#undef ROW8
#undef UPD
#undef LOADSET

    // ---- epilogue: f16 pair-reduce -> f32, + bias, store ----
    const int rowbase = blockIdx.x * BM + ty;
    #pragma unroll
    for (int n = 0; n < 8; ++n) {
        float b = bias[tx + 16 * n];
        #pragma unroll
        for (int m = 0; m < 4; ++m) {
            h2 a = acc[m][n];
            out[(size_t)(rowbase + 16 * m) * 128 + tx + 16 * n] =
                fminf((float)a.x, (float)a.y) + b;
        }
    }
}

extern "C" void kernel_launch(void* const* d_in, const int* in_sizes, int n_in,
                              void* d_out, int out_size, void* d_ws, size_t ws_size,
                              hipStream_t stream) {
    const float* x    = (const float*)d_in[0];
    const float* w    = (const float*)d_in[1];
    const float* bias = (const float*)d_in[2];
    float* out = (float*)d_out;

    int nrows  = in_sizes[0] / K;            // 32768
    int blocks = nrows / BM;                 // 512 -> 2 blocks/CU
    minplus_kernel<<<blocks, 256, 0, stream>>>(x, w, bias, out);
}